// Round 1
// baseline (2183.088 us; speedup 1.0000x reference)
//
#include <hip/hip_runtime.h>
#include <hip/hip_bf16.h>

#define N_NODES 100000
#define IN_DIM 128
#define PE_DIM 16
#define F_IN 144      // IN+PE
#define HID 128
#define LAT 64
#define K_CHEB 4

// ---------------------------------------------------------------- utility
__global__ void zero_kernel(float* __restrict__ p, size_t n) {
    size_t i = (size_t)blockIdx.x * 256 + threadIdx.x;
    if (i < n) p[i] = 0.f;
}

// ---------------------------------------------------------------- graph prep
// deg[src] += w (self-loops zeroed), cnt[dst] += 1
__global__ void edge_pass1(const int* __restrict__ ei, const float* __restrict__ ew,
                           float* __restrict__ deg, int* __restrict__ cnt, int E) {
    int e = blockIdx.x * 256 + threadIdx.x;
    if (e >= E) return;
    int s = ei[e], d = ei[E + e];
    float w = (s == d) ? 0.f : ew[e];
    atomicAdd(&deg[s], w);
    atomicAdd(&cnt[d], 1);
}

__global__ void dinv_kernel(const float* __restrict__ deg, float* __restrict__ dinv, int n) {
    int i = blockIdx.x * 256 + threadIdx.x;
    if (i >= n) return;
    float d = deg[i];
    dinv[i] = (d > 0.f) ? rsqrtf(d) : 0.f;
}

// single-block exclusive scan of cnt[0..n) -> rowptr[0..n], copy into wcur
__global__ __launch_bounds__(1024) void scan_kernel(const int* __restrict__ cnt,
                                                    int* __restrict__ rowptr,
                                                    int* __restrict__ wcur, int n) {
    __shared__ int sdata[1024];
    __shared__ int carry;
    if (threadIdx.x == 0) carry = 0;
    __syncthreads();
    for (int base = 0; base < n; base += 1024) {
        int i = base + threadIdx.x;
        int v = (i < n) ? cnt[i] : 0;
        sdata[threadIdx.x] = v;
        __syncthreads();
        for (int off = 1; off < 1024; off <<= 1) {
            int t = (threadIdx.x >= off) ? sdata[threadIdx.x - off] : 0;
            __syncthreads();
            sdata[threadIdx.x] += t;
            __syncthreads();
        }
        int excl = sdata[threadIdx.x] - v;
        if (i < n) { int o = carry + excl; rowptr[i] = o; wcur[i] = o; }
        __syncthreads();
        if (threadIdx.x == 1023) carry += sdata[1023];
        __syncthreads();
    }
    if (threadIdx.x == 0) rowptr[n] = carry;
}

// fill CSR: slot = wcur[dst]++; csr_src[slot]=src; csr_w[slot]=w_hat
__global__ void fill_kernel(const int* __restrict__ ei, const float* __restrict__ ew,
                            const float* __restrict__ dinv, int* __restrict__ wcur,
                            int* __restrict__ csr_src, float* __restrict__ csr_w, int E) {
    int e = blockIdx.x * 256 + threadIdx.x;
    if (e >= E) return;
    int s = ei[e], d = ei[E + e];
    float w = (s == d) ? 0.f : ew[e];
    float wh = -dinv[s] * w * dinv[d];
    int slot = atomicAdd(&wcur[d], 1);
    csr_src[slot] = s;
    csr_w[slot] = wh;
}

// ---------------------------------------------------------------- concat
__global__ void concat_x(const float* __restrict__ x, float* __restrict__ h, size_t n) {
    size_t idx = (size_t)blockIdx.x * 256 + threadIdx.x;
    if (idx >= n) return;
    size_t i = idx >> 7; int f = (int)(idx & 127);
    h[i * F_IN + f] = x[idx];
}
__global__ void concat_pe(const float* __restrict__ pe, float* __restrict__ h, size_t n) {
    size_t idx = (size_t)blockIdx.x * 256 + threadIdx.x;
    if (idx >= n) return;
    size_t i = idx >> 4; int f = (int)(idx & 15);
    h[i * F_IN + 128 + f] = pe[idx];
}

// ---------------------------------------------------------------- propagate
// out[i,:] = recur ? 2*sum_e w_e*h[src_e,:] - told[i,:]  :  sum_e w_e*h[src_e,:]
template<int F>
__global__ __launch_bounds__(256) void prop_kernel(const float* __restrict__ h,
                                                   const float* __restrict__ told,
                                                   float* __restrict__ out,
                                                   const int* __restrict__ rowptr,
                                                   const int* __restrict__ csr_src,
                                                   const float* __restrict__ csr_w,
                                                   int n, int recur) {
    int node = blockIdx.x * 4 + (threadIdx.x >> 6);
    if (node >= n) return;
    int lane = threadIdx.x & 63;
    int e0 = rowptr[node], e1 = rowptr[node + 1];
    float a0 = 0.f, a1 = 0.f, a2 = 0.f;
    for (int e = e0; e < e1; ++e) {
        int s = csr_src[e];
        float wv = csr_w[e];
        const float* hp = h + (size_t)s * F;
        a0 += wv * hp[lane];
        a1 += wv * hp[64 + lane];
        if (F == 144) { if (lane < 16) a2 += wv * hp[128 + lane]; }
    }
    float* op = out + (size_t)node * F;
    const float* tp = told + (size_t)node * F;
    if (recur) {
        op[lane]      = 2.f * a0 - tp[lane];
        op[64 + lane] = 2.f * a1 - tp[64 + lane];
        if (F == 144) { if (lane < 16) op[128 + lane] = 2.f * a2 - tp[128 + lane]; }
    } else {
        op[lane]      = a0;
        op[64 + lane] = a1;
        if (F == 144) { if (lane < 16) op[128 + lane] = a2; }
    }
}

// ---------------------------------------------------------------- GEMM
// C[M x 128] (ACC? += : =) A[M x F] @ W[F x 128]
template<int F, bool ACC>
__global__ __launch_bounds__(256) void gemm_kernel(const float* __restrict__ A,
                                                   const float* __restrict__ W,
                                                   float* __restrict__ C, int M) {
    constexpr int FP = F + 4;
    __shared__ float As[64 * FP];
    int tid = threadIdx.x;
    int m0 = blockIdx.x * 64;
    constexpr int NV = F / 4;
    constexpr int TOT = 64 * NV;
    for (int idx = tid; idx < TOT; idx += 256) {
        int r = idx / NV, q = idx - r * NV;
        float4 v = make_float4(0.f, 0.f, 0.f, 0.f);
        int row = m0 + r;
        if (row < M) v = *(const float4*)(A + (size_t)row * F + q * 4);
        *(float4*)(&As[r * FP + q * 4]) = v;
    }
    __syncthreads();
    int c0 = (tid & 31) * 4;
    int r0 = (tid >> 5) * 8;
    float acc[8][4];
#pragma unroll
    for (int r = 0; r < 8; r++)
#pragma unroll
        for (int c = 0; c < 4; c++) acc[r][c] = 0.f;
    for (int k0 = 0; k0 < F; k0 += 4) {
        float4 w0 = *(const float4*)(W + (size_t)(k0 + 0) * 128 + c0);
        float4 w1 = *(const float4*)(W + (size_t)(k0 + 1) * 128 + c0);
        float4 w2 = *(const float4*)(W + (size_t)(k0 + 2) * 128 + c0);
        float4 w3 = *(const float4*)(W + (size_t)(k0 + 3) * 128 + c0);
#pragma unroll
        for (int r = 0; r < 8; r++) {
            float4 a = *(const float4*)(&As[(r0 + r) * FP + k0]);
            acc[r][0] += a.x * w0.x + a.y * w1.x + a.z * w2.x + a.w * w3.x;
            acc[r][1] += a.x * w0.y + a.y * w1.y + a.z * w2.y + a.w * w3.y;
            acc[r][2] += a.x * w0.z + a.y * w1.z + a.z * w2.z + a.w * w3.z;
            acc[r][3] += a.x * w0.w + a.y * w1.w + a.z * w2.w + a.w * w3.w;
        }
    }
#pragma unroll
    for (int r = 0; r < 8; r++) {
        int row = m0 + r0 + r;
        if (row < M) {
            float* cp = C + (size_t)row * 128 + c0;
            float4 o;
            if (ACC) {
                float4 old = *(const float4*)cp;
                o = make_float4(old.x + acc[r][0], old.y + acc[r][1],
                                old.z + acc[r][2], old.w + acc[r][3]);
            } else {
                o = make_float4(acc[r][0], acc[r][1], acc[r][2], acc[r][3]);
            }
            *(float4*)cp = o;
        }
    }
}

// ---------------------------------------------------------------- epilogue
__global__ void bias_relu(float* __restrict__ h, const float* __restrict__ b, size_t n) {
    size_t i = (size_t)blockIdx.x * 256 + threadIdx.x;
    if (i >= n) return;
    float v = h[i] + b[i & 127];
    h[i] = v > 0.f ? v : 0.f;
}

__global__ __launch_bounds__(256) void colmean_kernel(const float* __restrict__ h,
                                                      float* __restrict__ g, int n) {
    __shared__ float s[256];
    int tid = threadIdx.x;
    int col = tid & 127;
    int rg = tid >> 7;
    int rbase = blockIdx.x * 256;
    float local = 0.f;
    for (int r = rbase + rg; r < rbase + 256 && r < n; r += 2)
        local += h[(size_t)r * 128 + col];
    s[tid] = local;
    __syncthreads();
    if (tid < 128) atomicAdd(&g[col], s[tid] + s[tid + 128]);
}

__global__ void head_kernel(const float* __restrict__ g,
                            const float* __restrict__ Wmu, const float* __restrict__ bmu,
                            const float* __restrict__ Wlv, const float* __restrict__ blv,
                            float* __restrict__ out, float invN) {
    __shared__ float gm[128];
    int tid = threadIdx.x;
    gm[tid] = g[tid] * invN;
    __syncthreads();
    if (tid < 64) {
        float acc = bmu[tid];
        for (int i = 0; i < 128; i++) acc += gm[i] * Wmu[i * 64 + tid];
        out[tid] = acc;
    } else {
        int j = tid - 64;
        float acc = blv[j];
        for (int i = 0; i < 128; i++) acc += gm[i] * Wlv[i * 64 + j];
        out[64 + j] = acc;
    }
}

// ---------------------------------------------------------------- launch
static inline size_t align64(size_t x) { return (x + 63) & ~(size_t)63; }

extern "C" void kernel_launch(void* const* d_in, const int* in_sizes, int n_in,
                              void* d_out, int out_size, void* d_ws, size_t ws_size,
                              hipStream_t stream) {
    const float* x   = (const float*)d_in[0];
    const int*   ei  = (const int*)d_in[1];
    const float* pe  = (const float*)d_in[2];
    const float* ew  = (const float*)d_in[3];
    const float* W1  = (const float*)d_in[4];
    const float* b1  = (const float*)d_in[5];
    const float* W2  = (const float*)d_in[6];
    const float* b2  = (const float*)d_in[7];
    const float* Wmu = (const float*)d_in[8];
    const float* bmu = (const float*)d_in[9];
    const float* Wlv = (const float*)d_in[10];
    const float* blv = (const float*)d_in[11];
    float* out = (float*)d_out;

    const int N = in_sizes[0] / IN_DIM;
    const int E = in_sizes[3];

    float* ws = (float*)d_ws;
    // workspace layout (4-byte elements)
    size_t o_deg   = 0;                       // N floats
    size_t o_cnt   = o_deg + N;               // N ints
    size_t o_g     = o_cnt + N;               // 128 floats
    size_t zeroLen = o_g + 128;               // zero range [0, zeroLen)
    size_t o_dinv  = align64(zeroLen);        // N
    size_t o_rowp  = align64(o_dinv + N);     // N+1 ints
    size_t o_wcur  = align64(o_rowp + N + 1); // N ints
    size_t o_csrs  = align64(o_wcur + N);     // E ints
    size_t o_csrw  = align64(o_csrs + E);     // E floats
    size_t o_bufA  = align64(o_csrw + E);     // N*144
    size_t o_bufB  = align64(o_bufA + (size_t)N * F_IN); // N*144
    size_t o_h1    = align64(o_bufB + (size_t)N * F_IN); // N*128
    size_t o_out2  = align64(o_h1 + (size_t)N * HID);    // N*128

    float* deg   = ws + o_deg;
    int*   cnt   = (int*)(ws + o_cnt);
    float* g     = ws + o_g;
    float* dinv  = ws + o_dinv;
    int*   rowp  = (int*)(ws + o_rowp);
    int*   wcur  = (int*)(ws + o_wcur);
    int*   csrs  = (int*)(ws + o_csrs);
    float* csrw  = ws + o_csrw;
    float* bufA  = ws + o_bufA;
    float* bufB  = ws + o_bufB;
    float* h1    = ws + o_h1;
    float* out2  = ws + o_out2;

    dim3 b256(256);

    // graph prep
    zero_kernel<<<dim3((unsigned)((zeroLen + 255) / 256)), b256, 0, stream>>>(ws, zeroLen);
    edge_pass1<<<dim3((E + 255) / 256), b256, 0, stream>>>(ei, ew, deg, cnt, E);
    dinv_kernel<<<dim3((N + 255) / 256), b256, 0, stream>>>(deg, dinv, N);
    scan_kernel<<<dim3(1), dim3(1024), 0, stream>>>(cnt, rowp, wcur, N);
    fill_kernel<<<dim3((E + 255) / 256), b256, 0, stream>>>(ei, ew, dinv, wcur, csrs, csrw, E);

    // concat h = [x, pe]
    concat_x<<<dim3((unsigned)(((size_t)N * 128 + 255) / 256)), b256, 0, stream>>>(x, bufA, (size_t)N * 128);
    concat_pe<<<dim3((unsigned)(((size_t)N * 16 + 255) / 256)), b256, 0, stream>>>(pe, bufA, (size_t)N * 16);

    const unsigned gemmGrid = (unsigned)((N + 63) / 64);
    const unsigned propGrid = (unsigned)((N + 3) / 4);
    const unsigned nhGrid   = (unsigned)(((size_t)N * 128 + 255) / 256);

    // ---------------- layer 1 (F=144) ----------------
    gemm_kernel<F_IN, false><<<gemmGrid, b256, 0, stream>>>(bufA, W1 + 0 * F_IN * HID, h1, N);
    prop_kernel<F_IN><<<propGrid, b256, 0, stream>>>(bufA, bufA, bufB, rowp, csrs, csrw, N, 0); // T1 -> bufB
    gemm_kernel<F_IN, true><<<gemmGrid, b256, 0, stream>>>(bufB, W1 + 1 * F_IN * HID, h1, N);
    prop_kernel<F_IN><<<propGrid, b256, 0, stream>>>(bufB, bufA, bufA, rowp, csrs, csrw, N, 1); // T2 -> bufA
    gemm_kernel<F_IN, true><<<gemmGrid, b256, 0, stream>>>(bufA, W1 + 2 * F_IN * HID, h1, N);
    prop_kernel<F_IN><<<propGrid, b256, 0, stream>>>(bufA, bufB, bufB, rowp, csrs, csrw, N, 1); // T3 -> bufB
    gemm_kernel<F_IN, true><<<gemmGrid, b256, 0, stream>>>(bufB, W1 + 3 * F_IN * HID, h1, N);
    bias_relu<<<nhGrid, b256, 0, stream>>>(h1, b1, (size_t)N * HID);

    // ---------------- layer 2 (F=128) ----------------
    gemm_kernel<HID, false><<<gemmGrid, b256, 0, stream>>>(h1, W2 + 0 * HID * HID, out2, N);
    prop_kernel<HID><<<propGrid, b256, 0, stream>>>(h1, h1, bufA, rowp, csrs, csrw, N, 0);      // T1 -> bufA
    gemm_kernel<HID, true><<<gemmGrid, b256, 0, stream>>>(bufA, W2 + 1 * HID * HID, out2, N);
    prop_kernel<HID><<<propGrid, b256, 0, stream>>>(bufA, h1, bufB, rowp, csrs, csrw, N, 1);    // T2 -> bufB
    gemm_kernel<HID, true><<<gemmGrid, b256, 0, stream>>>(bufB, W2 + 2 * HID * HID, out2, N);
    prop_kernel<HID><<<propGrid, b256, 0, stream>>>(bufB, bufA, bufA, rowp, csrs, csrw, N, 1);  // T3 -> bufA
    gemm_kernel<HID, true><<<gemmGrid, b256, 0, stream>>>(bufA, W2 + 3 * HID * HID, out2, N);
    bias_relu<<<nhGrid, b256, 0, stream>>>(out2, b2, (size_t)N * HID);

    // pool + heads
    colmean_kernel<<<dim3((N + 255) / 256), b256, 0, stream>>>(out2, g, N);
    head_kernel<<<dim3(1), dim3(128), 0, stream>>>(g, Wmu, bmu, Wlv, blv, out, 1.0f / (float)N);
}

// Round 2
// 1504.237 us; speedup vs baseline: 1.4513x; 1.4513x over previous
//
#include <hip/hip_runtime.h>
#include <hip/hip_bf16.h>

#define IN_DIM 128
#define PE_DIM 16
#define F_IN 144      // IN+PE
#define HID 128
#define LAT 64
#define K_CHEB 4

typedef unsigned int uint;
typedef unsigned short ushort;
typedef __attribute__((ext_vector_type(8))) short short8;
typedef __attribute__((ext_vector_type(4))) float floatx4;

// ---------------------------------------------------------------- bf16 helpers
__device__ __forceinline__ ushort f2bf(float f) {
    uint u = __float_as_uint(f);
    uint r = (u + 0x7FFFu + ((u >> 16) & 1u)) >> 16;   // RNE
    return (ushort)r;
}
__device__ __forceinline__ float bf_lo(uint v) { return __uint_as_float(v << 16); }
__device__ __forceinline__ float bf_hi(uint v) { return __uint_as_float(v & 0xFFFF0000u); }
__device__ __forceinline__ uint bf_pack(float lo, float hi) {
    return (uint)f2bf(lo) | ((uint)f2bf(hi) << 16);
}

// ---------------------------------------------------------------- utility
__global__ void zero_kernel(float* __restrict__ p, size_t n) {
    size_t i = (size_t)blockIdx.x * 256 + threadIdx.x;
    if (i < n) p[i] = 0.f;
}

// ---------------------------------------------------------------- graph prep
__global__ void edge_pass1(const int* __restrict__ ei, const float* __restrict__ ew,
                           float* __restrict__ deg, int* __restrict__ cnt, int E) {
    int e = blockIdx.x * 256 + threadIdx.x;
    if (e >= E) return;
    int s = ei[e], d = ei[E + e];
    float w = (s == d) ? 0.f : ew[e];
    atomicAdd(&deg[s], w);
    atomicAdd(&cnt[d], 1);
}

__global__ void dinv_kernel(const float* __restrict__ deg, float* __restrict__ dinv, int n) {
    int i = blockIdx.x * 256 + threadIdx.x;
    if (i >= n) return;
    float d = deg[i];
    dinv[i] = (d > 0.f) ? rsqrtf(d) : 0.f;
}

// hierarchical scan: k1 per-block sums, k2 scan of partials (single block), k3 local scan+offset
__global__ __launch_bounds__(256) void scan_part(const int* __restrict__ cnt,
                                                 int* __restrict__ psum, int n) {
    __shared__ int s[256];
    int tid = threadIdx.x;
    int base = blockIdx.x * 1024 + tid * 4;
    int t = 0;
#pragma unroll
    for (int j = 0; j < 4; j++) { int i = base + j; t += (i < n) ? cnt[i] : 0; }
    s[tid] = t;
    __syncthreads();
    for (int off = 128; off > 0; off >>= 1) {
        if (tid < off) s[tid] += s[tid + off];
        __syncthreads();
    }
    if (tid == 0) psum[blockIdx.x] = s[0];
}

__global__ __launch_bounds__(128) void scan_psum(int* __restrict__ psum,
                                                 int* __restrict__ rowp, int nb, int n) {
    __shared__ int s[128];
    int tid = threadIdx.x;
    int v = (tid < nb) ? psum[tid] : 0;
    s[tid] = v;
    __syncthreads();
    for (int off = 1; off < 128; off <<= 1) {
        int t = (tid >= off) ? s[tid - off] : 0;
        __syncthreads();
        s[tid] += t;
        __syncthreads();
    }
    if (tid < nb) psum[tid] = s[tid] - v;       // exclusive
    if (tid == 127) rowp[n] = s[127];           // total = E
}

__global__ __launch_bounds__(256) void scan_local(const int* __restrict__ cnt,
                                                  const int* __restrict__ psum,
                                                  int* __restrict__ rowp,
                                                  int* __restrict__ wcur, int n) {
    __shared__ int s[256];
    int tid = threadIdx.x;
    int base = blockIdx.x * 1024 + tid * 4;
    int v[4];
    int tsum = 0;
#pragma unroll
    for (int j = 0; j < 4; j++) { int i = base + j; v[j] = (i < n) ? cnt[i] : 0; tsum += v[j]; }
    s[tid] = tsum;
    __syncthreads();
    for (int off = 1; off < 256; off <<= 1) {
        int t = (tid >= off) ? s[tid - off] : 0;
        __syncthreads();
        s[tid] += t;
        __syncthreads();
    }
    int run = s[tid] - tsum + psum[blockIdx.x];
#pragma unroll
    for (int j = 0; j < 4; j++) {
        int i = base + j;
        if (i < n) { rowp[i] = run; wcur[i] = run; }
        run += v[j];
    }
}

__global__ void fill_kernel(const int* __restrict__ ei, const float* __restrict__ ew,
                            const float* __restrict__ dinv, int* __restrict__ wcur,
                            int* __restrict__ csr_src, float* __restrict__ csr_w, int E) {
    int e = blockIdx.x * 256 + threadIdx.x;
    if (e >= E) return;
    int s = ei[e], d = ei[E + e];
    float w = (s == d) ? 0.f : ew[e];
    float wh = -dinv[s] * w * dinv[d];
    int slot = atomicAdd(&wcur[d], 1);
    csr_src[slot] = s;
    csr_w[slot] = wh;
}

// ---------------------------------------------------------------- concat -> bf16 Tcat1 slice 0
// Tcat1 row stride 576 bf16 = 288 uint-pairs; x -> pairs [0,64), pe -> pairs [64,72)
__global__ void concat_x_bf(const float* __restrict__ x, uint* __restrict__ T, size_t np) {
    size_t idx = (size_t)blockIdx.x * 256 + threadIdx.x;
    if (idx >= np) return;
    size_t i = idx >> 6; int p = (int)(idx & 63);
    float2 v = *(const float2*)(x + i * 128 + p * 2);
    T[i * 288 + p] = bf_pack(v.x, v.y);
}
__global__ void concat_pe_bf(const float* __restrict__ pe, uint* __restrict__ T, size_t np) {
    size_t idx = (size_t)blockIdx.x * 256 + threadIdx.x;
    if (idx >= np) return;
    size_t i = idx >> 3; int p = (int)(idx & 7);
    float2 v = *(const float2*)(pe + i * 16 + p * 2);
    T[i * 288 + 64 + p] = bf_pack(v.x, v.y);
}

// ---------------------------------------------------------------- W -> Bt bf16 transpose
// Bt[n][kk] = bf16(W[kk*128 + n]),  n in [0,128), kk in [0,K)
template<int K>
__global__ void wconv_kernel(const float* __restrict__ W, ushort* __restrict__ Bt) {
    int idx = blockIdx.x * 256 + threadIdx.x;
    if (idx >= 128 * K) return;
    int n = idx / K, kk = idx - n * K;
    Bt[idx] = f2bf(W[(size_t)kk * 128 + n]);
}

// ---------------------------------------------------------------- propagate (bf16 in/out, fp32 accum)
// out slice = recur ? 2*sum_e w_e*T[src, src_slice] - T[node, old_slice] : sum
// offsets in uint(=bf162 pair) units; P = row stride in pairs
template<int F, int P>
__global__ __launch_bounds__(256) void prop_bf(const ushort* __restrict__ Tu,
                                               int off_src, int off_dst, int off_old,
                                               int recur,
                                               const int* __restrict__ rowp,
                                               const int* __restrict__ csrs,
                                               const float* __restrict__ csrw, int n) {
    int node = blockIdx.x * 4 + (threadIdx.x >> 6);
    if (node >= n) return;
    int lane = threadIdx.x & 63;
    int e0 = rowp[node], e1 = rowp[node + 1];
    const uint* T = (const uint*)Tu;
    const uint* Tsrc = T + off_src;
    float ax = 0.f, ay = 0.f, bx = 0.f, by = 0.f;
    for (int e = e0; e < e1; ++e) {
        int s = csrs[e];
        float w = csrw[e];
        const uint* hp = Tsrc + (size_t)s * P;
        uint v = hp[lane];
        ax += w * bf_lo(v);
        ay += w * bf_hi(v);
        if (F == 144) {
            if (lane < 8) {
                uint v2 = hp[64 + lane];
                bx += w * bf_lo(v2);
                by += w * bf_hi(v2);
            }
        }
    }
    uint* op = (uint*)T + off_dst + (size_t)node * P;
    if (recur) {
        const uint* tp = T + off_old + (size_t)node * P;
        uint ov = tp[lane];
        ax = 2.f * ax - bf_lo(ov);
        ay = 2.f * ay - bf_hi(ov);
        op[lane] = bf_pack(ax, ay);
        if (F == 144) {
            if (lane < 8) {
                uint ov2 = tp[64 + lane];
                bx = 2.f * bx - bf_lo(ov2);
                by = 2.f * by - bf_hi(ov2);
                op[64 + lane] = bf_pack(bx, by);
            }
        }
    } else {
        op[lane] = bf_pack(ax, ay);
        if (F == 144) { if (lane < 8) op[64 + lane] = bf_pack(bx, by); }
    }
}

// ---------------------------------------------------------------- MFMA GEMM
// C[M,128] = relu(A[M,K] @ B[K,128] + bias)
//   REDUCE=false: store bf16 into Cb with row stride CS (bf16 units)
//   REDUCE=true : column-sum into g[128] (global mean pool numerator)
// A bf16 row-major [M][K]; Bt bf16 [128][K] (pre-transposed)
template<int K, bool REDUCE>
__global__ __launch_bounds__(256) void gemm_mfma(const ushort* __restrict__ A,
                                                 const ushort* __restrict__ Bt,
                                                 const float* __restrict__ bias,
                                                 ushort* __restrict__ Cb,
                                                 float* __restrict__ g,
                                                 int M, int CS) {
    __shared__ ushort As[64 * 40];    // 64 rows x 32k, stride 40 (pad)
    __shared__ ushort Bs[128 * 40];   // 128 cols x 32k, stride 40
    __shared__ float colsum[128];
    int tid = threadIdx.x;
    int m0 = blockIdx.x * 64;
    int lane = tid & 63, wv = tid >> 6;
    int quad = lane >> 4, mrow = lane & 15;

    floatx4 acc[8];
#pragma unroll
    for (int c = 0; c < 8; c++) acc[c] = (floatx4){0.f, 0.f, 0.f, 0.f};
    if (REDUCE) { if (tid < 128) colsum[tid] = 0.f; }

    int ar = tid >> 2, ak = (tid & 3) * 8;   // A staging: row, k-offset
    int bn = tid >> 1, bk = (tid & 1) * 16;  // B staging: col-row, k-offset

    for (int k0 = 0; k0 < K; k0 += 32) {
        __syncthreads();
        short8 av = (short8){0, 0, 0, 0, 0, 0, 0, 0};
        if (m0 + ar < M)
            av = *(const short8*)(A + (size_t)(m0 + ar) * K + k0 + ak);
        *(short8*)(&As[ar * 40 + ak]) = av;
        *(short8*)(&Bs[bn * 40 + bk]) = *(const short8*)(Bt + (size_t)bn * K + k0 + bk);
        *(short8*)(&Bs[bn * 40 + bk + 8]) = *(const short8*)(Bt + (size_t)bn * K + k0 + bk + 8);
        __syncthreads();
        short8 af = *(const short8*)(&As[(wv * 16 + mrow) * 40 + quad * 8]);
#pragma unroll
        for (int c = 0; c < 8; c++) {
            short8 bf = *(const short8*)(&Bs[(c * 16 + mrow) * 40 + quad * 8]);
            acc[c] = __builtin_amdgcn_mfma_f32_16x16x32_bf16(af, bf, acc[c], 0, 0, 0);
        }
    }

#pragma unroll
    for (int c = 0; c < 8; c++) {
        int col = c * 16 + mrow;
        float bsv = bias[col];
        if (REDUCE) {
            float part = 0.f;
#pragma unroll
            for (int r = 0; r < 4; r++) {
                int row = m0 + wv * 16 + quad * 4 + r;
                if (row < M) {
                    float v = acc[c][r] + bsv;
                    part += (v > 0.f) ? v : 0.f;
                }
            }
            part += __shfl_xor(part, 16);
            part += __shfl_xor(part, 32);
            if (quad == 0 && wv == 0) { /* placeholder to keep structure clear */ }
            if (quad == 0) atomicAdd(&colsum[col], part);
        } else {
#pragma unroll
            for (int r = 0; r < 4; r++) {
                int row = m0 + wv * 16 + quad * 4 + r;
                if (row < M) {
                    float v = acc[c][r] + bsv;
                    v = (v > 0.f) ? v : 0.f;
                    Cb[(size_t)row * CS + col] = f2bf(v);
                }
            }
        }
    }
    if (REDUCE) {
        __syncthreads();
        if (tid < 128) atomicAdd(&g[tid], colsum[tid]);
    }
}

// ---------------------------------------------------------------- head
__global__ void head_kernel(const float* __restrict__ g,
                            const float* __restrict__ Wmu, const float* __restrict__ bmu,
                            const float* __restrict__ Wlv, const float* __restrict__ blv,
                            float* __restrict__ out, float invN) {
    __shared__ float gm[128];
    int tid = threadIdx.x;
    gm[tid] = g[tid] * invN;
    __syncthreads();
    if (tid < 64) {
        float acc = bmu[tid];
        for (int i = 0; i < 128; i++) acc += gm[i] * Wmu[i * 64 + tid];
        out[tid] = acc;
    } else {
        int j = tid - 64;
        float acc = blv[j];
        for (int i = 0; i < 128; i++) acc += gm[i] * Wlv[i * 64 + j];
        out[64 + j] = acc;
    }
}

// ---------------------------------------------------------------- launch
static inline size_t align64(size_t x) { return (x + 63) & ~(size_t)63; }

extern "C" void kernel_launch(void* const* d_in, const int* in_sizes, int n_in,
                              void* d_out, int out_size, void* d_ws, size_t ws_size,
                              hipStream_t stream) {
    const float* x   = (const float*)d_in[0];
    const int*   ei  = (const int*)d_in[1];
    const float* pe  = (const float*)d_in[2];
    const float* ew  = (const float*)d_in[3];
    const float* W1  = (const float*)d_in[4];
    const float* b1  = (const float*)d_in[5];
    const float* W2  = (const float*)d_in[6];
    const float* b2  = (const float*)d_in[7];
    const float* Wmu = (const float*)d_in[8];
    const float* bmu = (const float*)d_in[9];
    const float* Wlv = (const float*)d_in[10];
    const float* blv = (const float*)d_in[11];
    float* out = (float*)d_out;

    const int N = in_sizes[0] / IN_DIM;
    const int E = in_sizes[3];
    const int NB = (N + 1023) / 1024;          // scan blocks (<=128)

    float* ws = (float*)d_ws;
    // workspace layout in 4-byte units
    size_t o_deg  = 0;                          // N floats
    size_t o_cnt  = o_deg + N;                  // N ints
    size_t o_g    = o_cnt + N;                  // 128 floats
    size_t zeroLen = o_g + 128;
    size_t o_dinv = align64(zeroLen);           // N
    size_t o_rowp = align64(o_dinv + N);        // N+1
    size_t o_wcur = align64(o_rowp + N + 1);    // N
    size_t o_psum = align64(o_wcur + N);        // 128
    size_t o_csrs = align64(o_psum + 128);      // E
    size_t o_csrw = align64(o_csrs + E);        // E
    size_t o_Bt1  = align64(o_csrw + E);        // 128*576 bf16 = 36864 u32
    size_t o_Bt2  = align64(o_Bt1 + 128 * 576 / 2);   // 128*512 bf16 = 32768 u32
    size_t o_T1   = align64(o_Bt2 + 128 * 512 / 2);   // N*576 bf16 = N*288 u32
    size_t o_T2   = align64(o_T1 + (size_t)N * 288);  // N*512 bf16 = N*256 u32

    float* deg   = ws + o_deg;
    int*   cnt   = (int*)(ws + o_cnt);
    float* g     = ws + o_g;
    float* dinv  = ws + o_dinv;
    int*   rowp  = (int*)(ws + o_rowp);
    int*   wcur  = (int*)(ws + o_wcur);
    int*   psum  = (int*)(ws + o_psum);
    int*   csrs  = (int*)(ws + o_csrs);
    float* csrw  = ws + o_csrw;
    ushort* Bt1  = (ushort*)(ws + o_Bt1);
    ushort* Bt2  = (ushort*)(ws + o_Bt2);
    ushort* T1   = (ushort*)(ws + o_T1);
    ushort* T2   = (ushort*)(ws + o_T2);

    dim3 b256(256);

    // ---- graph prep
    zero_kernel<<<dim3((unsigned)((zeroLen + 255) / 256)), b256, 0, stream>>>(ws, zeroLen);
    edge_pass1<<<dim3((E + 255) / 256), b256, 0, stream>>>(ei, ew, deg, cnt, E);
    dinv_kernel<<<dim3((N + 255) / 256), b256, 0, stream>>>(deg, dinv, N);
    scan_part<<<dim3(NB), b256, 0, stream>>>(cnt, psum, N);
    scan_psum<<<dim3(1), dim3(128), 0, stream>>>(psum, rowp, NB, N);
    scan_local<<<dim3(NB), b256, 0, stream>>>(cnt, psum, rowp, wcur, N);
    fill_kernel<<<dim3((E + 255) / 256), b256, 0, stream>>>(ei, ew, dinv, wcur, csrs, csrw, E);

    // ---- weights -> bf16 transposed
    wconv_kernel<576><<<dim3((128 * 576 + 255) / 256), b256, 0, stream>>>(W1, Bt1);
    wconv_kernel<512><<<dim3((128 * 512 + 255) / 256), b256, 0, stream>>>(W2, Bt2);

    // ---- T1 slice 0 = [x, pe] in bf16
    concat_x_bf<<<dim3((unsigned)(((size_t)N * 64 + 255) / 256)), b256, 0, stream>>>(x, (uint*)T1, (size_t)N * 64);
    concat_pe_bf<<<dim3((unsigned)(((size_t)N * 8 + 255) / 256)), b256, 0, stream>>>(pe, (uint*)T1, (size_t)N * 8);

    const unsigned propGrid = (unsigned)((N + 3) / 4);
    const unsigned gemmGrid = (unsigned)((N + 63) / 64);

    // ---- layer 1: T1 slices (pair offsets: slice k at k*72), F=144, P=288
    prop_bf<144, 288><<<propGrid, b256, 0, stream>>>(T1, 0,   72,  0,   0, rowp, csrs, csrw, N);
    prop_bf<144, 288><<<propGrid, b256, 0, stream>>>(T1, 72,  144, 0,   1, rowp, csrs, csrw, N);
    prop_bf<144, 288><<<propGrid, b256, 0, stream>>>(T1, 144, 216, 72,  1, rowp, csrs, csrw, N);
    // GEMM1: [N,576]@[576,128] -> relu+bias -> bf16 into T2 slice 0 (stride 512)
    gemm_mfma<576, false><<<gemmGrid, b256, 0, stream>>>(T1, Bt1, b1, T2, g, N, 512);

    // ---- layer 2: T2 slices (pair offsets k*64), F=128, P=256
    prop_bf<128, 256><<<propGrid, b256, 0, stream>>>(T2, 0,   64,  0,   0, rowp, csrs, csrw, N);
    prop_bf<128, 256><<<propGrid, b256, 0, stream>>>(T2, 64,  128, 0,   1, rowp, csrs, csrw, N);
    prop_bf<128, 256><<<propGrid, b256, 0, stream>>>(T2, 128, 192, 64,  1, rowp, csrs, csrw, N);
    // GEMM2: [N,512]@[512,128] -> relu+bias -> column sums into g
    gemm_mfma<512, true><<<gemmGrid, b256, 0, stream>>>(T2, Bt2, b2, (ushort*)nullptr, g, N, 0);

    // ---- heads
    head_kernel<<<dim3(1), dim3(128), 0, stream>>>(g, Wmu, bmu, Wlv, blv, out, 1.0f / (float)N);
}

// Round 3
// 946.336 us; speedup vs baseline: 2.3069x; 1.5895x over previous
//
#include <hip/hip_runtime.h>
#include <hip/hip_bf16.h>

#define IN_DIM 128
#define PE_DIM 16
#define F_IN 144      // IN+PE
#define HID 128
#define LAT 64
#define K_CHEB 4

typedef unsigned int uint;
typedef unsigned short ushort;
typedef __attribute__((ext_vector_type(8))) short short8;
typedef __attribute__((ext_vector_type(4))) float floatx4;

// ---------------------------------------------------------------- bf16 helpers
__device__ __forceinline__ ushort f2bf(float f) {
    uint u = __float_as_uint(f);
    uint r = (u + 0x7FFFu + ((u >> 16) & 1u)) >> 16;   // RNE
    return (ushort)r;
}
__device__ __forceinline__ float bf_lo(uint v) { return __uint_as_float(v << 16); }
__device__ __forceinline__ float bf_hi(uint v) { return __uint_as_float(v & 0xFFFF0000u); }
__device__ __forceinline__ uint bf_pack(float lo, float hi) {
    return (uint)f2bf(lo) | ((uint)f2bf(hi) << 16);
}

// ---------------------------------------------------------------- utility
__global__ void zero_kernel(float* __restrict__ p, size_t n) {
    size_t i = (size_t)blockIdx.x * 256 + threadIdx.x;
    if (i < n) p[i] = 0.f;
}

// ---------------------------------------------------------------- graph prep
__global__ void edge_pass1(const int* __restrict__ ei, const float* __restrict__ ew,
                           float* __restrict__ deg, int* __restrict__ cnt, int E) {
    int e = blockIdx.x * 256 + threadIdx.x;
    if (e >= E) return;
    int s = ei[e], d = ei[E + e];
    float w = (s == d) ? 0.f : ew[e];
    atomicAdd(&deg[s], w);
    atomicAdd(&cnt[d], 1);
}

__global__ void dinv_kernel(const float* __restrict__ deg, float* __restrict__ dinv, int n) {
    int i = blockIdx.x * 256 + threadIdx.x;
    if (i >= n) return;
    float d = deg[i];
    dinv[i] = (d > 0.f) ? rsqrtf(d) : 0.f;
}

// hierarchical scan: k1 per-block sums, k2 scan of partials (single block), k3 local scan+offset
__global__ __launch_bounds__(256) void scan_part(const int* __restrict__ cnt,
                                                 int* __restrict__ psum, int n) {
    __shared__ int s[256];
    int tid = threadIdx.x;
    int base = blockIdx.x * 1024 + tid * 4;
    int t = 0;
#pragma unroll
    for (int j = 0; j < 4; j++) { int i = base + j; t += (i < n) ? cnt[i] : 0; }
    s[tid] = t;
    __syncthreads();
    for (int off = 128; off > 0; off >>= 1) {
        if (tid < off) s[tid] += s[tid + off];
        __syncthreads();
    }
    if (tid == 0) psum[blockIdx.x] = s[0];
}

__global__ __launch_bounds__(128) void scan_psum(int* __restrict__ psum,
                                                 int* __restrict__ rowp, int nb, int n) {
    __shared__ int s[128];
    int tid = threadIdx.x;
    int v = (tid < nb) ? psum[tid] : 0;
    s[tid] = v;
    __syncthreads();
    for (int off = 1; off < 128; off <<= 1) {
        int t = (tid >= off) ? s[tid - off] : 0;
        __syncthreads();
        s[tid] += t;
        __syncthreads();
    }
    if (tid < nb) psum[tid] = s[tid] - v;       // exclusive
    if (tid == 127) rowp[n] = s[127];           // total = E
}

__global__ __launch_bounds__(256) void scan_local(const int* __restrict__ cnt,
                                                  const int* __restrict__ psum,
                                                  int* __restrict__ rowp,
                                                  int* __restrict__ wcur, int n) {
    __shared__ int s[256];
    int tid = threadIdx.x;
    int base = blockIdx.x * 1024 + tid * 4;
    int v[4];
    int tsum = 0;
#pragma unroll
    for (int j = 0; j < 4; j++) { int i = base + j; v[j] = (i < n) ? cnt[i] : 0; tsum += v[j]; }
    s[tid] = tsum;
    __syncthreads();
    for (int off = 1; off < 256; off <<= 1) {
        int t = (tid >= off) ? s[tid - off] : 0;
        __syncthreads();
        s[tid] += t;
        __syncthreads();
    }
    int run = s[tid] - tsum + psum[blockIdx.x];
#pragma unroll
    for (int j = 0; j < 4; j++) {
        int i = base + j;
        if (i < n) { rowp[i] = run; wcur[i] = run; }
        run += v[j];
    }
}

__global__ void fill_kernel(const int* __restrict__ ei, const float* __restrict__ ew,
                            const float* __restrict__ dinv, int* __restrict__ wcur,
                            int* __restrict__ csr_src, float* __restrict__ csr_w, int E) {
    int e = blockIdx.x * 256 + threadIdx.x;
    if (e >= E) return;
    int s = ei[e], d = ei[E + e];
    float w = (s == d) ? 0.f : ew[e];
    float wh = -dinv[s] * w * dinv[d];
    int slot = atomicAdd(&wcur[d], 1);
    csr_src[slot] = s;
    csr_w[slot] = wh;
}

// ---------------------------------------------------------------- concat -> bf16 T1 slice 0
__global__ void concat_x_bf(const float* __restrict__ x, uint* __restrict__ T, size_t np) {
    size_t idx = (size_t)blockIdx.x * 256 + threadIdx.x;
    if (idx >= np) return;
    size_t i = idx >> 6; int p = (int)(idx & 63);
    float2 v = *(const float2*)(x + i * 128 + p * 2);
    T[i * 288 + p] = bf_pack(v.x, v.y);
}
__global__ void concat_pe_bf(const float* __restrict__ pe, uint* __restrict__ T, size_t np) {
    size_t idx = (size_t)blockIdx.x * 256 + threadIdx.x;
    if (idx >= np) return;
    size_t i = idx >> 3; int p = (int)(idx & 7);
    float2 v = *(const float2*)(pe + i * 16 + p * 2);
    T[i * 288 + 64 + p] = bf_pack(v.x, v.y);
}

// ---------------------------------------------------------------- W -> Bt bf16 transpose
template<int K>
__global__ void wconv_kernel(const float* __restrict__ W, ushort* __restrict__ Bt) {
    int idx = blockIdx.x * 256 + threadIdx.x;
    if (idx >= 128 * K) return;
    int n = idx / K, kk = idx - n * K;
    Bt[idx] = f2bf(W[(size_t)kk * 128 + n]);
}

// ---------------------------------------------------------------- propagate (MLP-optimized)
// One wave per node. 64 lanes = 4 edge-groups x 16 lanes; each lane gathers uint4
// (8 bf16) of its edge's source row; 8 edges in flight per iteration (unroll 2).
// Edge metadata batch-loaded (64 at a time) and broadcast via shfl.
// out slice = recur ? 2*sum - told : sum. Offsets/strides in uint units.
template<int F, int P>
__global__ __launch_bounds__(256) void prop_bf(const ushort* __restrict__ Tu,
                                               int off_src, int off_dst, int off_old,
                                               int recur,
                                               const int* __restrict__ rowp,
                                               const int* __restrict__ csrs,
                                               const float* __restrict__ csrw, int n) {
    int node = blockIdx.x * 4 + (threadIdx.x >> 6);
    if (node >= n) return;
    int lane = threadIdx.x & 63;
    int g = lane >> 4;          // edge sub-group 0..3
    int ll = lane & 15;         // lane within group
    int e0 = rowp[node], e1 = rowp[node + 1];

    const uint* T = (const uint*)Tu;
    const uint* Tsrc = T + off_src;

    float acc[8];
#pragma unroll
    for (int i = 0; i < 8; i++) acc[i] = 0.f;
    float ex0 = 0.f, ex1 = 0.f;   // extra 8 uints for F=144

    for (int base = e0; base < e1; base += 64) {
        int degc = e1 - base; if (degc > 64) degc = 64;
        int sidx = 0; float wval = 0.f;
        if (lane < degc) { sidx = csrs[base + lane]; wval = csrw[base + lane]; }
        for (int j = 0; j < degc; j += 8) {
            int j0 = j + g, j1 = j0 + 4;
            int   s0 = __shfl(sidx, j0), s1 = __shfl(sidx, j1);
            float w0 = __shfl(wval, j0), w1 = __shfl(wval, j1);
            const uint* hp0 = Tsrc + (size_t)s0 * P;
            const uint* hp1 = Tsrc + (size_t)s1 * P;
            uint4 v0 = *(const uint4*)(hp0 + ll * 4);
            uint4 v1 = *(const uint4*)(hp1 + ll * 4);
            uint x0 = 0, x1 = 0;
            if (F == 144) {
                if (ll < 8) { x0 = hp0[64 + ll]; x1 = hp1[64 + ll]; }
            }
            acc[0] += w0 * bf_lo(v0.x); acc[1] += w0 * bf_hi(v0.x);
            acc[2] += w0 * bf_lo(v0.y); acc[3] += w0 * bf_hi(v0.y);
            acc[4] += w0 * bf_lo(v0.z); acc[5] += w0 * bf_hi(v0.z);
            acc[6] += w0 * bf_lo(v0.w); acc[7] += w0 * bf_hi(v0.w);
            acc[0] += w1 * bf_lo(v1.x); acc[1] += w1 * bf_hi(v1.x);
            acc[2] += w1 * bf_lo(v1.y); acc[3] += w1 * bf_hi(v1.y);
            acc[4] += w1 * bf_lo(v1.z); acc[5] += w1 * bf_hi(v1.z);
            acc[6] += w1 * bf_lo(v1.w); acc[7] += w1 * bf_hi(v1.w);
            if (F == 144) {
                ex0 += w0 * bf_lo(x0) + w1 * bf_lo(x1);
                ex1 += w0 * bf_hi(x0) + w1 * bf_hi(x1);
            }
        }
    }

    // reduce across the 4 edge-groups (xor 16/32 preserves ll)
#pragma unroll
    for (int i = 0; i < 8; i++) {
        acc[i] += __shfl_xor(acc[i], 16);
        acc[i] += __shfl_xor(acc[i], 32);
    }
    if (F == 144) {
        ex0 += __shfl_xor(ex0, 16); ex0 += __shfl_xor(ex0, 32);
        ex1 += __shfl_xor(ex1, 16); ex1 += __shfl_xor(ex1, 32);
    }

    if (g == 0) {
        uint* op = (uint*)T + off_dst + (size_t)node * P;
        const uint* tp = T + off_old + (size_t)node * P;
        if (recur) {
            uint4 ov = *(const uint4*)(tp + ll * 4);
            acc[0] = 2.f * acc[0] - bf_lo(ov.x); acc[1] = 2.f * acc[1] - bf_hi(ov.x);
            acc[2] = 2.f * acc[2] - bf_lo(ov.y); acc[3] = 2.f * acc[3] - bf_hi(ov.y);
            acc[4] = 2.f * acc[4] - bf_lo(ov.z); acc[5] = 2.f * acc[5] - bf_hi(ov.z);
            acc[6] = 2.f * acc[6] - bf_lo(ov.w); acc[7] = 2.f * acc[7] - bf_hi(ov.w);
            if (F == 144 && ll < 8) {
                uint ox = tp[64 + ll];
                ex0 = 2.f * ex0 - bf_lo(ox);
                ex1 = 2.f * ex1 - bf_hi(ox);
            }
        }
        uint4 o;
        o.x = bf_pack(acc[0], acc[1]);
        o.y = bf_pack(acc[2], acc[3]);
        o.z = bf_pack(acc[4], acc[5]);
        o.w = bf_pack(acc[6], acc[7]);
        *(uint4*)(op + ll * 4) = o;
        if (F == 144 && ll < 8) op[64 + ll] = bf_pack(ex0, ex1);
    }
}

// ---------------------------------------------------------------- MFMA GEMM
// C[M,128] = relu(A[M,K] @ B[K,128] + bias)
//   REDUCE=false: store bf16 into Cb with row stride CS (bf16 units)
//   REDUCE=true : column-sum into g[128] (global mean pool numerator)
template<int K, bool REDUCE>
__global__ __launch_bounds__(256) void gemm_mfma(const ushort* __restrict__ A,
                                                 const ushort* __restrict__ Bt,
                                                 const float* __restrict__ bias,
                                                 ushort* __restrict__ Cb,
                                                 float* __restrict__ g,
                                                 int M, int CS) {
    __shared__ ushort As[64 * 40];    // 64 rows x 32k, stride 40 (pad)
    __shared__ ushort Bs[128 * 40];   // 128 cols x 32k, stride 40
    __shared__ float colsum[128];
    int tid = threadIdx.x;
    int m0 = blockIdx.x * 64;
    int lane = tid & 63, wv = tid >> 6;
    int quad = lane >> 4, mrow = lane & 15;

    floatx4 acc[8];
#pragma unroll
    for (int c = 0; c < 8; c++) acc[c] = (floatx4){0.f, 0.f, 0.f, 0.f};
    if (REDUCE) { if (tid < 128) colsum[tid] = 0.f; }

    int ar = tid >> 2, ak = (tid & 3) * 8;   // A staging: row, k-offset
    int bn = tid >> 1, bk = (tid & 1) * 16;  // B staging: col-row, k-offset

    for (int k0 = 0; k0 < K; k0 += 32) {
        __syncthreads();
        short8 av = (short8){0, 0, 0, 0, 0, 0, 0, 0};
        if (m0 + ar < M)
            av = *(const short8*)(A + (size_t)(m0 + ar) * K + k0 + ak);
        *(short8*)(&As[ar * 40 + ak]) = av;
        *(short8*)(&Bs[bn * 40 + bk]) = *(const short8*)(Bt + (size_t)bn * K + k0 + bk);
        *(short8*)(&Bs[bn * 40 + bk + 8]) = *(const short8*)(Bt + (size_t)bn * K + k0 + bk + 8);
        __syncthreads();
        short8 af = *(const short8*)(&As[(wv * 16 + mrow) * 40 + quad * 8]);
#pragma unroll
        for (int c = 0; c < 8; c++) {
            short8 bf = *(const short8*)(&Bs[(c * 16 + mrow) * 40 + quad * 8]);
            acc[c] = __builtin_amdgcn_mfma_f32_16x16x32_bf16(af, bf, acc[c], 0, 0, 0);
        }
    }

#pragma unroll
    for (int c = 0; c < 8; c++) {
        int col = c * 16 + mrow;
        float bsv = bias[col];
        if (REDUCE) {
            float part = 0.f;
#pragma unroll
            for (int r = 0; r < 4; r++) {
                int row = m0 + wv * 16 + quad * 4 + r;
                if (row < M) {
                    float v = acc[c][r] + bsv;
                    part += (v > 0.f) ? v : 0.f;
                }
            }
            part += __shfl_xor(part, 16);
            part += __shfl_xor(part, 32);
            if (quad == 0) atomicAdd(&colsum[col], part);
        } else {
#pragma unroll
            for (int r = 0; r < 4; r++) {
                int row = m0 + wv * 16 + quad * 4 + r;
                if (row < M) {
                    float v = acc[c][r] + bsv;
                    v = (v > 0.f) ? v : 0.f;
                    Cb[(size_t)row * CS + col] = f2bf(v);
                }
            }
        }
    }
    if (REDUCE) {
        __syncthreads();
        if (tid < 128) atomicAdd(&g[tid], colsum[tid]);
    }
}

// ---------------------------------------------------------------- head
__global__ void head_kernel(const float* __restrict__ g,
                            const float* __restrict__ Wmu, const float* __restrict__ bmu,
                            const float* __restrict__ Wlv, const float* __restrict__ blv,
                            float* __restrict__ out, float invN) {
    __shared__ float gm[128];
    int tid = threadIdx.x;
    gm[tid] = g[tid] * invN;
    __syncthreads();
    if (tid < 64) {
        float acc = bmu[tid];
        for (int i = 0; i < 128; i++) acc += gm[i] * Wmu[i * 64 + tid];
        out[tid] = acc;
    } else {
        int j = tid - 64;
        float acc = blv[j];
        for (int i = 0; i < 128; i++) acc += gm[i] * Wlv[i * 64 + j];
        out[64 + j] = acc;
    }
}

// ---------------------------------------------------------------- launch
static inline size_t align64(size_t x) { return (x + 63) & ~(size_t)63; }

extern "C" void kernel_launch(void* const* d_in, const int* in_sizes, int n_in,
                              void* d_out, int out_size, void* d_ws, size_t ws_size,
                              hipStream_t stream) {
    const float* x   = (const float*)d_in[0];
    const int*   ei  = (const int*)d_in[1];
    const float* pe  = (const float*)d_in[2];
    const float* ew  = (const float*)d_in[3];
    const float* W1  = (const float*)d_in[4];
    const float* b1  = (const float*)d_in[5];
    const float* W2  = (const float*)d_in[6];
    const float* b2  = (const float*)d_in[7];
    const float* Wmu = (const float*)d_in[8];
    const float* bmu = (const float*)d_in[9];
    const float* Wlv = (const float*)d_in[10];
    const float* blv = (const float*)d_in[11];
    float* out = (float*)d_out;

    const int N = in_sizes[0] / IN_DIM;
    const int E = in_sizes[3];
    const int NB = (N + 1023) / 1024;          // scan blocks (<=128)

    float* ws = (float*)d_ws;
    size_t o_deg  = 0;                          // N floats
    size_t o_cnt  = o_deg + N;                  // N ints
    size_t o_g    = o_cnt + N;                  // 128 floats
    size_t zeroLen = o_g + 128;
    size_t o_dinv = align64(zeroLen);           // N
    size_t o_rowp = align64(o_dinv + N);        // N+1
    size_t o_wcur = align64(o_rowp + N + 1);    // N
    size_t o_psum = align64(o_wcur + N);        // 128
    size_t o_csrs = align64(o_psum + 128);      // E
    size_t o_csrw = align64(o_csrs + E);        // E
    size_t o_Bt1  = align64(o_csrw + E);        // 128*576 bf16
    size_t o_Bt2  = align64(o_Bt1 + 128 * 576 / 2);   // 128*512 bf16
    size_t o_T1   = align64(o_Bt2 + 128 * 512 / 2);   // N*288 u32
    size_t o_T2   = align64(o_T1 + (size_t)N * 288);  // N*256 u32

    float* deg   = ws + o_deg;
    int*   cnt   = (int*)(ws + o_cnt);
    float* g     = ws + o_g;
    float* dinv  = ws + o_dinv;
    int*   rowp  = (int*)(ws + o_rowp);
    int*   wcur  = (int*)(ws + o_wcur);
    int*   psum  = (int*)(ws + o_psum);
    int*   csrs  = (int*)(ws + o_csrs);
    float* csrw  = ws + o_csrw;
    ushort* Bt1  = (ushort*)(ws + o_Bt1);
    ushort* Bt2  = (ushort*)(ws + o_Bt2);
    ushort* T1   = (ushort*)(ws + o_T1);
    ushort* T2   = (ushort*)(ws + o_T2);

    dim3 b256(256);

    // ---- graph prep
    zero_kernel<<<dim3((unsigned)((zeroLen + 255) / 256)), b256, 0, stream>>>(ws, zeroLen);
    edge_pass1<<<dim3((E + 255) / 256), b256, 0, stream>>>(ei, ew, deg, cnt, E);
    dinv_kernel<<<dim3((N + 255) / 256), b256, 0, stream>>>(deg, dinv, N);
    scan_part<<<dim3(NB), b256, 0, stream>>>(cnt, psum, N);
    scan_psum<<<dim3(1), dim3(128), 0, stream>>>(psum, rowp, NB, N);
    scan_local<<<dim3(NB), b256, 0, stream>>>(cnt, psum, rowp, wcur, N);
    fill_kernel<<<dim3((E + 255) / 256), b256, 0, stream>>>(ei, ew, dinv, wcur, csrs, csrw, E);

    // ---- weights -> bf16 transposed
    wconv_kernel<576><<<dim3((128 * 576 + 255) / 256), b256, 0, stream>>>(W1, Bt1);
    wconv_kernel<512><<<dim3((128 * 512 + 255) / 256), b256, 0, stream>>>(W2, Bt2);

    // ---- T1 slice 0 = [x, pe] in bf16
    concat_x_bf<<<dim3((unsigned)(((size_t)N * 64 + 255) / 256)), b256, 0, stream>>>(x, (uint*)T1, (size_t)N * 64);
    concat_pe_bf<<<dim3((unsigned)(((size_t)N * 8 + 255) / 256)), b256, 0, stream>>>(pe, (uint*)T1, (size_t)N * 8);

    const unsigned propGrid = (unsigned)((N + 3) / 4);
    const unsigned gemmGrid = (unsigned)((N + 63) / 64);

    // ---- layer 1: T1 slices (uint offsets k*72), F=144, P=288
    prop_bf<144, 288><<<propGrid, b256, 0, stream>>>(T1, 0,   72,  0,   0, rowp, csrs, csrw, N);
    prop_bf<144, 288><<<propGrid, b256, 0, stream>>>(T1, 72,  144, 0,   1, rowp, csrs, csrw, N);
    prop_bf<144, 288><<<propGrid, b256, 0, stream>>>(T1, 144, 216, 72,  1, rowp, csrs, csrw, N);
    gemm_mfma<576, false><<<gemmGrid, b256, 0, stream>>>(T1, Bt1, b1, T2, g, N, 512);

    // ---- layer 2: T2 slices (uint offsets k*64), F=128, P=256
    prop_bf<128, 256><<<propGrid, b256, 0, stream>>>(T2, 0,   64,  0,   0, rowp, csrs, csrw, N);
    prop_bf<128, 256><<<propGrid, b256, 0, stream>>>(T2, 64,  128, 0,   1, rowp, csrs, csrw, N);
    prop_bf<128, 256><<<propGrid, b256, 0, stream>>>(T2, 128, 192, 64,  1, rowp, csrs, csrw, N);
    gemm_mfma<512, true><<<gemmGrid, b256, 0, stream>>>(T2, Bt2, b2, (ushort*)nullptr, g, N, 0);

    // ---- heads
    head_kernel<<<dim3(1), dim3(128), 0, stream>>>(g, Wmu, bmu, Wlv, blv, out, 1.0f / (float)N);
}

// Round 4
// 802.573 us; speedup vs baseline: 2.7201x; 1.1791x over previous
//
#include <hip/hip_runtime.h>
#include <hip/hip_bf16.h>

#define IN_DIM 128
#define PE_DIM 16
#define F_IN 144      // IN+PE
#define HID 128
#define LAT 64
#define K_CHEB 4

typedef unsigned int uint;
typedef unsigned short ushort;
typedef __attribute__((ext_vector_type(8))) short short8;
typedef __attribute__((ext_vector_type(4))) float floatx4;

// ---------------------------------------------------------------- bf16 helpers
__device__ __forceinline__ ushort f2bf(float f) {
    uint u = __float_as_uint(f);
    uint r = (u + 0x7FFFu + ((u >> 16) & 1u)) >> 16;   // RNE
    return (ushort)r;
}
__device__ __forceinline__ float bf_lo(uint v) { return __uint_as_float(v << 16); }
__device__ __forceinline__ float bf_hi(uint v) { return __uint_as_float(v & 0xFFFF0000u); }
__device__ __forceinline__ uint bf_pack(float lo, float hi) {
    return (uint)f2bf(lo) | ((uint)f2bf(hi) << 16);
}

// ---------------------------------------------------------------- utility
__global__ void zero_kernel(float* __restrict__ p, size_t n) {
    size_t i = (size_t)blockIdx.x * 256 + threadIdx.x;
    if (i < n) p[i] = 0.f;
}

// ================================================================ graph prep
// 512-node buckets; NBUCK = ceil(N/512) <= 256. Per-edge global atomics are
// replaced by per-(block,bucket) reservations + LDS ranking.

// ---- histogram by src (A) and dst (B): ~196 global atomics per block
__global__ __launch_bounds__(256) void bin_hist(const int* __restrict__ ei,
                                                int* __restrict__ ghA,
                                                int* __restrict__ ghB, int E) {
    __shared__ int hA[256], hB[256];
    int t = threadIdx.x;
    hA[t] = 0; hB[t] = 0;
    __syncthreads();
    int base = blockIdx.x * 4096;
#pragma unroll
    for (int j = 0; j < 16; j++) {
        int e = base + t + j * 256;
        if (e < E) {
            int s = ei[e], d = ei[E + e];
            atomicAdd(&hA[s >> 9], 1);
            atomicAdd(&hB[d >> 9], 1);
        }
    }
    __syncthreads();
    atomicAdd(&ghA[t], hA[t]);
    atomicAdd(&ghB[t], hB[t]);
}

// ---- scan both histograms -> bucket bases (bb*[257]) + mutable cursors
__global__ __launch_bounds__(256) void bin_scan(const int* __restrict__ ghA,
                                                const int* __restrict__ ghB,
                                                int* __restrict__ bbA, int* __restrict__ curA,
                                                int* __restrict__ bbB, int* __restrict__ curB) {
    __shared__ int s[256];
    int t = threadIdx.x;
    int v = ghA[t];
    s[t] = v; __syncthreads();
    for (int off = 1; off < 256; off <<= 1) {
        int u = (t >= off) ? s[t - off] : 0;
        __syncthreads(); s[t] += u; __syncthreads();
    }
    bbA[t] = s[t] - v; curA[t] = s[t] - v;
    if (t == 255) bbA[256] = s[255];
    __syncthreads();
    int v2 = ghB[t];
    s[t] = v2; __syncthreads();
    for (int off = 1; off < 256; off <<= 1) {
        int u = (t >= off) ? s[t - off] : 0;
        __syncthreads(); s[t] += u; __syncthreads();
    }
    bbB[t] = s[t] - v2; curB[t] = s[t] - v2;
    if (t == 255) bbB[256] = s[255];
}

// ---- scatter edges into bucket-grouped stream (LDS local-shuffle, coalesced out)
// BYDST=0: key=src, record=(src, w)   [deg stream]
// BYDST=1: key=dst, record=(src | dstLow<<17, w)   [csr stream]
template<int BYDST>
__global__ __launch_bounds__(256) void bin_scatter(const int* __restrict__ ei,
                                                   const float* __restrict__ ew,
                                                   int* __restrict__ cursor,
                                                   uint2* __restrict__ outS, int E) {
    __shared__ uint2 rec[4096];   // 32 KB
    __shared__ int pos[4096];     // 16 KB
    __shared__ int hist[256], hscan[256], hrun[256], baseG[256];
    int t = threadIdx.x;
    hist[t] = 0;
    __syncthreads();
    int base = blockIdx.x * 4096;
    int cntBlk = E - base; if (cntBlk > 4096) cntBlk = 4096;
#pragma unroll
    for (int j = 0; j < 16; j++) {
        int e = base + t + j * 256;
        if (e < E) {
            int s = ei[e], d = ei[E + e];
            int key = BYDST ? d : s;
            atomicAdd(&hist[key >> 9], 1);
        }
    }
    __syncthreads();
    int v = hist[t];
    hscan[t] = v; __syncthreads();
    for (int off = 1; off < 256; off <<= 1) {
        int u = (t >= off) ? hscan[t - off] : 0;
        __syncthreads(); hscan[t] += u; __syncthreads();
    }
    int excl = hscan[t] - v;
    hscan[t] = excl;
    baseG[t] = atomicAdd(&cursor[t], v);
    hrun[t] = excl;
    __syncthreads();
#pragma unroll
    for (int j = 0; j < 16; j++) {
        int e = base + t + j * 256;
        if (e < E) {
            int s = ei[e], d = ei[E + e];
            float w = (s == d) ? 0.f : ew[e];
            int key = BYDST ? d : s;
            int b = key >> 9;
            int slot = atomicAdd(&hrun[b], 1);
            uint2 r;
            r.x = BYDST ? ((uint)s | ((uint)(d & 511) << 17)) : (uint)s;
            r.y = __float_as_uint(w);
            rec[slot] = r;
            pos[slot] = baseG[b] + (slot - hscan[b]);
        }
    }
    __syncthreads();
    for (int sI = t; sI < cntBlk; sI += 256) outS[pos[sI]] = rec[sI];
}

// ---- per-bucket weighted out-degree -> dinv (fused rsqrt), no global atomics
__global__ __launch_bounds__(256) void deg_bucket(const uint2* __restrict__ sA,
                                                  const int* __restrict__ bbA,
                                                  float* __restrict__ dinv, int N) {
    __shared__ float dl[512];
    int b = blockIdx.x, t = threadIdx.x;
    dl[t] = 0.f; dl[t + 256] = 0.f;
    __syncthreads();
    int s0 = bbA[b], s1 = bbA[b + 1];
    for (int r = s0 + t; r < s1; r += 256) {
        uint2 rc = sA[r];
        atomicAdd(&dl[(int)rc.x - (b << 9)], __uint_as_float(rc.y));
    }
    __syncthreads();
    for (int i = t; i < 512; i += 256) {
        int node = (b << 9) + i;
        if (node < N) {
            float d = dl[i];
            dinv[node] = (d > 0.f) ? rsqrtf(d) : 0.f;
        }
    }
}

// ---- per-bucket CSR build: rowp + packed (src, w_hat) entries
__global__ __launch_bounds__(256) void csr_bucket(const uint2* __restrict__ sB,
                                                  const int* __restrict__ bbB,
                                                  const float* __restrict__ dinv,
                                                  int* __restrict__ rowp,
                                                  uint2* __restrict__ csr,
                                                  int N, int nbuck, int E) {
    __shared__ int cl[512], ol[512], orun[512];
    __shared__ float dvl[512];
    __shared__ int ps[256];
    int b = blockIdx.x, t = threadIdx.x;
    cl[t] = 0; cl[t + 256] = 0;
    for (int i = t; i < 512; i += 256) {
        int node = (b << 9) + i;
        dvl[i] = (node < N) ? dinv[node] : 0.f;
    }
    __syncthreads();
    int s0 = bbB[b], s1 = bbB[b + 1];
    for (int r = s0 + t; r < s1; r += 256)
        atomicAdd(&cl[(sB[r].x >> 17) & 511], 1);
    __syncthreads();
    int v0 = cl[2 * t], v1 = cl[2 * t + 1];
    int pv = v0 + v1;
    ps[t] = pv; __syncthreads();
    for (int off = 1; off < 256; off <<= 1) {
        int u = (t >= off) ? ps[t - off] : 0;
        __syncthreads(); ps[t] += u; __syncthreads();
    }
    int pexcl = ps[t] - pv;
    ol[2 * t] = pexcl;       ol[2 * t + 1] = pexcl + v0;
    orun[2 * t] = pexcl;     orun[2 * t + 1] = pexcl + v0;
    {
        int n0 = (b << 9) + 2 * t;
        if (n0 < N)     rowp[n0] = s0 + ol[2 * t];
        if (n0 + 1 < N) rowp[n0 + 1] = s0 + ol[2 * t + 1];
    }
    if (b == nbuck - 1 && t == 0) rowp[N] = E;
    __syncthreads();
    for (int r = s0 + t; r < s1; r += 256) {
        uint2 rc = sB[r];
        int src = rc.x & 0x1FFFF;
        int dl_ = (rc.x >> 17) & 511;
        float w = __uint_as_float(rc.y);
        int rank = atomicAdd(&orun[dl_], 1);
        float wh = -dinv[src] * w * dvl[dl_];
        uint2 o; o.x = (uint)src; o.y = __float_as_uint(wh);
        csr[s0 + rank] = o;
    }
}

// ---------------------------------------------------------------- concat -> bf16 T1 slice 0
__global__ void concat_x_bf(const float* __restrict__ x, uint* __restrict__ T, size_t np) {
    size_t idx = (size_t)blockIdx.x * 256 + threadIdx.x;
    if (idx >= np) return;
    size_t i = idx >> 6; int p = (int)(idx & 63);
    float2 v = *(const float2*)(x + i * 128 + p * 2);
    T[i * 288 + p] = bf_pack(v.x, v.y);
}
__global__ void concat_pe_bf(const float* __restrict__ pe, uint* __restrict__ T, size_t np) {
    size_t idx = (size_t)blockIdx.x * 256 + threadIdx.x;
    if (idx >= np) return;
    size_t i = idx >> 3; int p = (int)(idx & 7);
    float2 v = *(const float2*)(pe + i * 16 + p * 2);
    T[i * 288 + 64 + p] = bf_pack(v.x, v.y);
}

// ---------------------------------------------------------------- W -> Bt bf16 transpose
template<int K>
__global__ void wconv_kernel(const float* __restrict__ W, ushort* __restrict__ Bt) {
    int idx = blockIdx.x * 256 + threadIdx.x;
    if (idx >= 128 * K) return;
    int n = idx / K, kk = idx - n * K;
    Bt[idx] = f2bf(W[(size_t)kk * 128 + n]);
}

// ---------------------------------------------------------------- propagate (MLP-optimized)
// One wave per node; 4 edge-groups x 16 lanes; uint4 row gathers, 8 edges in flight.
// CSR entries are packed uint2 (src, w_hat).
template<int F, int P>
__global__ __launch_bounds__(256) void prop_bf(const ushort* __restrict__ Tu,
                                               int off_src, int off_dst, int off_old,
                                               int recur,
                                               const int* __restrict__ rowp,
                                               const uint2* __restrict__ csrE, int n) {
    int node = blockIdx.x * 4 + (threadIdx.x >> 6);
    if (node >= n) return;
    int lane = threadIdx.x & 63;
    int g = lane >> 4;          // edge sub-group 0..3
    int ll = lane & 15;         // lane within group
    int e0 = rowp[node], e1 = rowp[node + 1];

    const uint* T = (const uint*)Tu;
    const uint* Tsrc = T + off_src;

    float acc[8];
#pragma unroll
    for (int i = 0; i < 8; i++) acc[i] = 0.f;
    float ex0 = 0.f, ex1 = 0.f;   // extra 8 uints for F=144

    for (int base = e0; base < e1; base += 64) {
        int degc = e1 - base; if (degc > 64) degc = 64;
        int sidx = 0; float wval = 0.f;
        if (lane < degc) {
            uint2 rc = csrE[base + lane];
            sidx = (int)rc.x; wval = __uint_as_float(rc.y);
        }
        for (int j = 0; j < degc; j += 8) {
            int j0 = j + g, j1 = j0 + 4;
            int   s0 = __shfl(sidx, j0), s1 = __shfl(sidx, j1);
            float w0 = __shfl(wval, j0), w1 = __shfl(wval, j1);
            const uint* hp0 = Tsrc + (size_t)s0 * P;
            const uint* hp1 = Tsrc + (size_t)s1 * P;
            uint4 v0 = *(const uint4*)(hp0 + ll * 4);
            uint4 v1 = *(const uint4*)(hp1 + ll * 4);
            uint x0 = 0, x1 = 0;
            if (F == 144) {
                if (ll < 8) { x0 = hp0[64 + ll]; x1 = hp1[64 + ll]; }
            }
            acc[0] += w0 * bf_lo(v0.x); acc[1] += w0 * bf_hi(v0.x);
            acc[2] += w0 * bf_lo(v0.y); acc[3] += w0 * bf_hi(v0.y);
            acc[4] += w0 * bf_lo(v0.z); acc[5] += w0 * bf_hi(v0.z);
            acc[6] += w0 * bf_lo(v0.w); acc[7] += w0 * bf_hi(v0.w);
            acc[0] += w1 * bf_lo(v1.x); acc[1] += w1 * bf_hi(v1.x);
            acc[2] += w1 * bf_lo(v1.y); acc[3] += w1 * bf_hi(v1.y);
            acc[4] += w1 * bf_lo(v1.z); acc[5] += w1 * bf_hi(v1.z);
            acc[6] += w1 * bf_lo(v1.w); acc[7] += w1 * bf_hi(v1.w);
            if (F == 144) {
                ex0 += w0 * bf_lo(x0) + w1 * bf_lo(x1);
                ex1 += w0 * bf_hi(x0) + w1 * bf_hi(x1);
            }
        }
    }

#pragma unroll
    for (int i = 0; i < 8; i++) {
        acc[i] += __shfl_xor(acc[i], 16);
        acc[i] += __shfl_xor(acc[i], 32);
    }
    if (F == 144) {
        ex0 += __shfl_xor(ex0, 16); ex0 += __shfl_xor(ex0, 32);
        ex1 += __shfl_xor(ex1, 16); ex1 += __shfl_xor(ex1, 32);
    }

    if (g == 0) {
        uint* op = (uint*)T + off_dst + (size_t)node * P;
        const uint* tp = T + off_old + (size_t)node * P;
        if (recur) {
            uint4 ov = *(const uint4*)(tp + ll * 4);
            acc[0] = 2.f * acc[0] - bf_lo(ov.x); acc[1] = 2.f * acc[1] - bf_hi(ov.x);
            acc[2] = 2.f * acc[2] - bf_lo(ov.y); acc[3] = 2.f * acc[3] - bf_hi(ov.y);
            acc[4] = 2.f * acc[4] - bf_lo(ov.z); acc[5] = 2.f * acc[5] - bf_hi(ov.z);
            acc[6] = 2.f * acc[6] - bf_lo(ov.w); acc[7] = 2.f * acc[7] - bf_hi(ov.w);
            if (F == 144 && ll < 8) {
                uint ox = tp[64 + ll];
                ex0 = 2.f * ex0 - bf_lo(ox);
                ex1 = 2.f * ex1 - bf_hi(ox);
            }
        }
        uint4 o;
        o.x = bf_pack(acc[0], acc[1]);
        o.y = bf_pack(acc[2], acc[3]);
        o.z = bf_pack(acc[4], acc[5]);
        o.w = bf_pack(acc[6], acc[7]);
        *(uint4*)(op + ll * 4) = o;
        if (F == 144 && ll < 8) op[64 + ll] = bf_pack(ex0, ex1);
    }
}

// ---------------------------------------------------------------- MFMA GEMM
template<int K, bool REDUCE>
__global__ __launch_bounds__(256) void gemm_mfma(const ushort* __restrict__ A,
                                                 const ushort* __restrict__ Bt,
                                                 const float* __restrict__ bias,
                                                 ushort* __restrict__ Cb,
                                                 float* __restrict__ g,
                                                 int M, int CS) {
    __shared__ ushort As[64 * 40];
    __shared__ ushort Bs[128 * 40];
    __shared__ float colsum[128];
    int tid = threadIdx.x;
    int m0 = blockIdx.x * 64;
    int lane = tid & 63, wv = tid >> 6;
    int quad = lane >> 4, mrow = lane & 15;

    floatx4 acc[8];
#pragma unroll
    for (int c = 0; c < 8; c++) acc[c] = (floatx4){0.f, 0.f, 0.f, 0.f};
    if (REDUCE) { if (tid < 128) colsum[tid] = 0.f; }

    int ar = tid >> 2, ak = (tid & 3) * 8;
    int bn = tid >> 1, bk = (tid & 1) * 16;

    for (int k0 = 0; k0 < K; k0 += 32) {
        __syncthreads();
        short8 av = (short8){0, 0, 0, 0, 0, 0, 0, 0};
        if (m0 + ar < M)
            av = *(const short8*)(A + (size_t)(m0 + ar) * K + k0 + ak);
        *(short8*)(&As[ar * 40 + ak]) = av;
        *(short8*)(&Bs[bn * 40 + bk]) = *(const short8*)(Bt + (size_t)bn * K + k0 + bk);
        *(short8*)(&Bs[bn * 40 + bk + 8]) = *(const short8*)(Bt + (size_t)bn * K + k0 + bk + 8);
        __syncthreads();
        short8 af = *(const short8*)(&As[(wv * 16 + mrow) * 40 + quad * 8]);
#pragma unroll
        for (int c = 0; c < 8; c++) {
            short8 bf = *(const short8*)(&Bs[(c * 16 + mrow) * 40 + quad * 8]);
            acc[c] = __builtin_amdgcn_mfma_f32_16x16x32_bf16(af, bf, acc[c], 0, 0, 0);
        }
    }

#pragma unroll
    for (int c = 0; c < 8; c++) {
        int col = c * 16 + mrow;
        float bsv = bias[col];
        if (REDUCE) {
            float part = 0.f;
#pragma unroll
            for (int r = 0; r < 4; r++) {
                int row = m0 + wv * 16 + quad * 4 + r;
                if (row < M) {
                    float v = acc[c][r] + bsv;
                    part += (v > 0.f) ? v : 0.f;
                }
            }
            part += __shfl_xor(part, 16);
            part += __shfl_xor(part, 32);
            if (quad == 0) atomicAdd(&colsum[col], part);
        } else {
#pragma unroll
            for (int r = 0; r < 4; r++) {
                int row = m0 + wv * 16 + quad * 4 + r;
                if (row < M) {
                    float v = acc[c][r] + bsv;
                    v = (v > 0.f) ? v : 0.f;
                    Cb[(size_t)row * CS + col] = f2bf(v);
                }
            }
        }
    }
    if (REDUCE) {
        __syncthreads();
        if (tid < 128) atomicAdd(&g[tid], colsum[tid]);
    }
}

// ---------------------------------------------------------------- head
__global__ void head_kernel(const float* __restrict__ g,
                            const float* __restrict__ Wmu, const float* __restrict__ bmu,
                            const float* __restrict__ Wlv, const float* __restrict__ blv,
                            float* __restrict__ out, float invN) {
    __shared__ float gm[128];
    int tid = threadIdx.x;
    gm[tid] = g[tid] * invN;
    __syncthreads();
    if (tid < 64) {
        float acc = bmu[tid];
        for (int i = 0; i < 128; i++) acc += gm[i] * Wmu[i * 64 + tid];
        out[tid] = acc;
    } else {
        int j = tid - 64;
        float acc = blv[j];
        for (int i = 0; i < 128; i++) acc += gm[i] * Wlv[i * 64 + j];
        out[64 + j] = acc;
    }
}

// ---------------------------------------------------------------- launch
static inline size_t align64(size_t x) { return (x + 63) & ~(size_t)63; }

extern "C" void kernel_launch(void* const* d_in, const int* in_sizes, int n_in,
                              void* d_out, int out_size, void* d_ws, size_t ws_size,
                              hipStream_t stream) {
    const float* x   = (const float*)d_in[0];
    const int*   ei  = (const int*)d_in[1];
    const float* pe  = (const float*)d_in[2];
    const float* ew  = (const float*)d_in[3];
    const float* W1  = (const float*)d_in[4];
    const float* b1  = (const float*)d_in[5];
    const float* W2  = (const float*)d_in[6];
    const float* b2  = (const float*)d_in[7];
    const float* Wmu = (const float*)d_in[8];
    const float* bmu = (const float*)d_in[9];
    const float* Wlv = (const float*)d_in[10];
    const float* blv = (const float*)d_in[11];
    float* out = (float*)d_out;

    const int N = in_sizes[0] / IN_DIM;
    const int E = in_sizes[3];
    const int NBUCK = (N + 511) >> 9;           // 196 for N=100000 (<=256)
    const int NBLK  = (E + 4095) / 4096;        // 391 for E=1.6M

    float* ws = (float*)d_ws;
    // workspace layout in 4-byte units
    size_t o_g    = 0;                           // 128 (pool accumulator)
    size_t o_ghA  = o_g + 128;                   // 256
    size_t o_ghB  = o_ghA + 256;                 // 256
    size_t zeroLen = o_ghB + 256;                // zero [0, 640)
    size_t o_bbA  = align64(zeroLen);            // 257
    size_t o_curA = align64(o_bbA + 257);        // 256
    size_t o_bbB  = align64(o_curA + 256);       // 257
    size_t o_curB = align64(o_bbB + 257);        // 256
    size_t o_rowp = align64(o_curB + 256);       // N+1
    size_t o_dinv = align64(o_rowp + N + 1);     // N
    size_t o_sA   = align64(o_dinv + N);         // 2E (uint2 stream, by src)
    size_t o_sB   = align64(o_sA + 2 * (size_t)E);   // 2E (uint2 stream, by dst)
    size_t o_csr  = align64(o_sB + 2 * (size_t)E);   // 2E (uint2 final CSR)
    size_t o_Bt1  = align64(o_csr + 2 * (size_t)E);  // 128*576 bf16
    size_t o_Bt2  = align64(o_Bt1 + 128 * 576 / 2);  // 128*512 bf16
    size_t o_T1   = align64(o_Bt2 + 128 * 512 / 2);  // N*288 u32
    size_t o_T2   = align64(o_T1 + (size_t)N * 288); // N*256 u32

    float* g     = ws + o_g;
    int*   ghA   = (int*)(ws + o_ghA);
    int*   ghB   = (int*)(ws + o_ghB);
    int*   bbA   = (int*)(ws + o_bbA);
    int*   curA  = (int*)(ws + o_curA);
    int*   bbB   = (int*)(ws + o_bbB);
    int*   curB  = (int*)(ws + o_curB);
    int*   rowp  = (int*)(ws + o_rowp);
    float* dinv  = ws + o_dinv;
    uint2* sA    = (uint2*)(ws + o_sA);
    uint2* sB    = (uint2*)(ws + o_sB);
    uint2* csr   = (uint2*)(ws + o_csr);
    ushort* Bt1  = (ushort*)(ws + o_Bt1);
    ushort* Bt2  = (ushort*)(ws + o_Bt2);
    ushort* T1   = (ushort*)(ws + o_T1);
    ushort* T2   = (ushort*)(ws + o_T2);

    dim3 b256(256);

    // ---- graph prep (bucket binning, no per-edge global atomics)
    zero_kernel<<<dim3((unsigned)((zeroLen + 255) / 256)), b256, 0, stream>>>(ws, zeroLen);
    bin_hist<<<dim3(NBLK), b256, 0, stream>>>(ei, ghA, ghB, E);
    bin_scan<<<dim3(1), b256, 0, stream>>>(ghA, ghB, bbA, curA, bbB, curB);
    bin_scatter<0><<<dim3(NBLK), b256, 0, stream>>>(ei, ew, curA, sA, E);
    deg_bucket<<<dim3(NBUCK), b256, 0, stream>>>(sA, bbA, dinv, N);
    bin_scatter<1><<<dim3(NBLK), b256, 0, stream>>>(ei, ew, curB, sB, E);
    csr_bucket<<<dim3(NBUCK), b256, 0, stream>>>(sB, bbB, dinv, rowp, csr, N, NBUCK, E);

    // ---- weights -> bf16 transposed
    wconv_kernel<576><<<dim3((128 * 576 + 255) / 256), b256, 0, stream>>>(W1, Bt1);
    wconv_kernel<512><<<dim3((128 * 512 + 255) / 256), b256, 0, stream>>>(W2, Bt2);

    // ---- T1 slice 0 = [x, pe] in bf16
    concat_x_bf<<<dim3((unsigned)(((size_t)N * 64 + 255) / 256)), b256, 0, stream>>>(x, (uint*)T1, (size_t)N * 64);
    concat_pe_bf<<<dim3((unsigned)(((size_t)N * 8 + 255) / 256)), b256, 0, stream>>>(pe, (uint*)T1, (size_t)N * 8);

    const unsigned propGrid = (unsigned)((N + 3) / 4);
    const unsigned gemmGrid = (unsigned)((N + 63) / 64);

    // ---- layer 1: T1 slices (uint offsets k*72), F=144, P=288
    prop_bf<144, 288><<<propGrid, b256, 0, stream>>>(T1, 0,   72,  0,   0, rowp, csr, N);
    prop_bf<144, 288><<<propGrid, b256, 0, stream>>>(T1, 72,  144, 0,   1, rowp, csr, N);
    prop_bf<144, 288><<<propGrid, b256, 0, stream>>>(T1, 144, 216, 72,  1, rowp, csr, N);
    gemm_mfma<576, false><<<gemmGrid, b256, 0, stream>>>(T1, Bt1, b1, T2, g, N, 512);

    // ---- layer 2: T2 slices (uint offsets k*64), F=128, P=256
    prop_bf<128, 256><<<propGrid, b256, 0, stream>>>(T2, 0,   64,  0,   0, rowp, csr, N);
    prop_bf<128, 256><<<propGrid, b256, 0, stream>>>(T2, 64,  128, 0,   1, rowp, csr, N);
    prop_bf<128, 256><<<propGrid, b256, 0, stream>>>(T2, 128, 192, 64,  1, rowp, csr, N);
    gemm_mfma<512, true><<<gemmGrid, b256, 0, stream>>>(T2, Bt2, b2, (ushort*)nullptr, g, N, 0);

    // ---- heads
    head_kernel<<<dim3(1), dim3(128), 0, stream>>>(g, Wmu, bmu, Wlv, blv, out, 1.0f / (float)N);
}